// Round 6
// baseline (94.765 us; speedup 1.0000x reference)
//
#include <hip/hip_runtime.h>

#define S 2048
#define B 2
#define H 1024
#define NH 16
#define HD 64
#define THREE_H 3072
#define ROWS (S*B)   // 4096

typedef __attribute__((ext_vector_type(8))) short short8;
typedef __attribute__((ext_vector_type(4))) float f32x4;
typedef const __attribute__((address_space(1))) unsigned int* gptr_t;
typedef __attribute__((address_space(3))) unsigned int* lptr_t;

#define N8_A (ROWS * H / 8)        // 524288
#define N8_W (THREE_H * H / 8)     // 393216

__device__ __forceinline__ ushort f2bf(float f) {
    union { float f; unsigned u; } v; v.f = f;
    unsigned r = v.u + 0x7fffu + ((v.u >> 16) & 1u);
    return (ushort)(r >> 16);
}
__device__ __forceinline__ float bf2f(ushort u) {
    union { unsigned u; float f; } v; v.u = ((unsigned)u) << 16;
    return v.f;
}

// ---------------------------------------------------------------------------
// Cast f32 -> bf16 for A and W in one launch
// ---------------------------------------------------------------------------
__global__ void cast_both(const float* __restrict__ A, const float* __restrict__ W,
                          ushort* __restrict__ Ab, ushort* __restrict__ Wb) {
    int i = blockIdx.x * 256 + threadIdx.x;
    const float4* s4;
    ushort* dst;
    if (i < N8_A) { s4 = (const float4*)A; dst = Ab; }
    else if (i < N8_A + N8_W) { s4 = (const float4*)W; dst = Wb; i -= N8_A; }
    else return;
    float4 a = s4[2 * i], b = s4[2 * i + 1];
    short8 o;
    o[0] = f2bf(a.x); o[1] = f2bf(a.y); o[2] = f2bf(a.z); o[3] = f2bf(a.w);
    o[4] = f2bf(b.x); o[5] = f2bf(b.y); o[6] = f2bf(b.z); o[7] = f2bf(b.w);
    *(short8*)(dst + 8 * (size_t)i) = o;
}

// ---------------------------------------------------------------------------
// K1: bf16 MFMA GEMM. Outputs: Qb [bh][s][d]; Kt, Vraw [bh][d][t] (all bf16).
// All three go through an LDS repack buffer Ct that ALIASES the staging
// buffers (dead after the K-loop) -> LDS stays ~17.4 KB (occupancy).
// Each 64-col segment of the 128-col window is one (h, q/k/v) segment.
// ---------------------------------------------------------------------------
__global__ __launch_bounds__(256) void qkv_gemm_mfma(const ushort* __restrict__ Abf,
                                                     const ushort* __restrict__ Wbf,
                                                     const float* __restrict__ bias,
                                                     ushort* __restrict__ Qb,
                                                     ushort* __restrict__ Kt,
                                                     ushort* __restrict__ Vraw) {
    __shared__ ushort smem[64 * 136];            // 17408 B: staging + epilogue union
    ushort* Abuf = smem;                         // [128][32] = 4096 ushorts
    ushort* Bbuf = smem + 4096;                  // [128][32]
    ushort (*Ct)[136] = (ushort(*)[136])smem;    // 64 x 136 epilogue repack

    const int tid = threadIdx.x;
    const int wave = tid >> 6, lane = tid & 63;
    const int wr = wave >> 1, wc = wave & 1;
    const int row0 = blockIdx.x * 128;
    const int col0 = blockIdx.y * 128;

    f32x4 acc[4][4] = {};

    const int lrow = lane >> 2;        // 0..15
    const int lk   = (lane & 3) * 8;   // 0,8,16,24

    for (int k0 = 0; k0 < H; k0 += 32) {
#pragma unroll
        for (int p = 0; p < 2; ++p) {
            int c = wave * 2 + p;
            int row = c * 16 + lrow;
            __builtin_amdgcn_global_load_lds(
                (gptr_t)&Abf[(size_t)(row0 + row) * H + k0 + lk],
                (lptr_t)&Abuf[c * 512 + lane * 8], 16, 0, 0);
            __builtin_amdgcn_global_load_lds(
                (gptr_t)&Wbf[(size_t)(col0 + row) * H + k0 + lk],
                (lptr_t)&Bbuf[c * 512 + lane * 8], 16, 0, 0);
        }
        __syncthreads();

        short8 af[4], bfr[4];
#pragma unroll
        for (int m = 0; m < 4; ++m) {
            int ar = wr * 64 + m * 16 + (lane & 15);
            af[m] = *(const short8*)&Abuf[ar * 32 + (lane >> 4) * 8];
            int br = wc * 64 + m * 16 + (lane & 15);
            bfr[m] = *(const short8*)&Bbuf[br * 32 + (lane >> 4) * 8];
        }
#pragma unroll
        for (int m = 0; m < 4; ++m)
#pragma unroll
            for (int n = 0; n < 4; ++n)
                acc[m][n] = __builtin_amdgcn_mfma_f32_16x16x32_bf16(af[m], bfr[n], acc[m][n], 0, 0, 0);
        __syncthreads();
    }

    // ---- epilogue: two 64-col segments, each uniform (h, sel) ----
    const int il = lane & 15, g = lane >> 4;
    const int t_base = row0 >> 1;   // 64 sequence positions per block
#pragma unroll
    for (int sg = 0; sg < 2; ++sg) {
        const int cseg = col0 + sg * 64;
        const int h = cseg / 192, rem = cseg % 192;
        const int sel = rem >> 6;                  // 0=q 1=k 2=v, block-uniform
        if (wc == sg) {
            if (sel == 0) {
                // Q repack: Ct[s_local][b*64 + d]
#pragma unroll
                for (int n = 0; n < 4; ++n) {
                    int d = n * 16 + il;
                    float bv = bias[cseg + d];
#pragma unroll
                    for (int m = 0; m < 4; ++m) {
                        int lr0 = wr * 64 + m * 16 + g * 4;
#pragma unroll
                        for (int j = 0; j < 4; ++j) {
                            int lr = lr0 + j;
                            Ct[lr >> 1][(lr & 1) * 64 + d] = f2bf(acc[m][n][j] + bv);
                        }
                    }
                }
            } else {
                // K/V repack: Ct[d_col][b*64 + t_local]
#pragma unroll
                for (int n = 0; n < 4; ++n) {
                    int c = n * 16 + il;
                    float bv = bias[cseg + c];
#pragma unroll
                    for (int m = 0; m < 4; ++m) {
                        int t0 = wr * 32 + m * 8 + g * 2;   // even, local t
                        uint lo = (uint)f2bf(acc[m][n][0] + bv) |
                                  ((uint)f2bf(acc[m][n][2] + bv) << 16);
                        uint hi = (uint)f2bf(acc[m][n][1] + bv) |
                                  ((uint)f2bf(acc[m][n][3] + bv) << 16);
                        *(uint*)&Ct[c][t0]      = lo;   // b=0 rows
                        *(uint*)&Ct[c][64 + t0] = hi;   // b=1 rows
                    }
                }
            }
        }
        __syncthreads();
        {
            const int c = tid >> 2, sub = tid & 3, bb = sub >> 1, th = (sub & 1) * 32;
            const ushort* sp = &Ct[c][bb * 64 + th];
            ushort* op;
            if (sel == 0) {
                op = Qb + ((size_t)((bb * NH + h) * S) + t_base + c) * HD + th;
            } else {
                ushort* dst = (sel == 1) ? Kt : Vraw;
                op = dst + ((size_t)((bb * NH + h) * HD + c)) * S + t_base + th;
            }
#pragma unroll
            for (int q = 0; q < 4; ++q)
                *(short8*)(op + q * 8) = *(const short8*)(sp + q * 8);
        }
        __syncthreads();
    }
}

// ---------------------------------------------------------------------------
// V-suffix scan on Vraw [bh][d][t] bf16: t-contiguous 64B per thread.
// ---------------------------------------------------------------------------
__global__ void vsuf_chunksum(const ushort* __restrict__ Vraw, float* __restrict__ csum) {
    int idx = blockIdx.x * 256 + threadIdx.x;   // 131072
    int col = idx & 2047;                        // bh*64 + d
    int chunk = idx >> 11;                       // 0..63
    const ushort* vp = Vraw + (size_t)col * S + chunk * 32;
    float s = 0.f;
#pragma unroll
    for (int q = 0; q < 4; ++q) {
        short8 v = *(const short8*)(vp + q * 8);
#pragma unroll
        for (int k = 0; k < 8; ++k) s += bf2f((ushort)v[k]);
    }
    csum[chunk * 2048 + col] = s;
}

__global__ void vsuf_final(ushort* __restrict__ Vraw, const float* __restrict__ csum) {
    int idx = blockIdx.x * 256 + threadIdx.x;
    int col = idx & 2047;
    int chunk = idx >> 11;
    float acc = 0.f;
    for (int c = chunk + 1; c < 64; ++c) acc += csum[c * 2048 + col];
    ushort* vp = Vraw + (size_t)col * S + chunk * 32;
    float v[32];
#pragma unroll
    for (int q = 0; q < 4; ++q) {
        short8 x = *(const short8*)(vp + q * 8);
#pragma unroll
        for (int k = 0; k < 8; ++k) v[q * 8 + k] = bf2f((ushort)x[k]);
    }
#pragma unroll
    for (int tt = 31; tt >= 0; --tt) { acc += v[tt]; v[tt] = acc; }
#pragma unroll
    for (int q = 0; q < 4; ++q) {
        short8 o;
#pragma unroll
        for (int k = 0; k < 8; ++k) o[k] = f2bf(v[q * 8 + k]);
        *(short8*)(vp + q * 8) = o;
    }
}

// ---------------------------------------------------------------------------
// K3: M[i][j] = sum_t Kt[i][t]*Vsuf[j][t] via MFMA. 16 k-slices of 128 t.
// ---------------------------------------------------------------------------
__global__ __launch_bounds__(256) void kvm_mfma(const ushort* __restrict__ Kt,
                                                const ushort* __restrict__ Vt,
                                                float* __restrict__ Mpart) {
    const int bh = blockIdx.x, kb = blockIdx.y;
    const int tid = threadIdx.x, wave = tid >> 6, lane = tid & 63;
    const int slice = kb * 4 + wave;
    const ushort* Kp = Kt + (size_t)bh * HD * S;
    const ushort* Vp = Vt + (size_t)bh * HD * S;
    f32x4 acc[4][4] = {};
    const int il = lane & 15;
    const int tbase = slice * 128 + (lane >> 4) * 8;
#pragma unroll
    for (int ks = 0; ks < 4; ++ks) {
        const int t = tbase + ks * 32;
        short8 af[4], bfv[4];
#pragma unroll
        for (int m = 0; m < 4; ++m) af[m]  = *(const short8*)&Kp[(size_t)(m * 16 + il) * S + t];
#pragma unroll
        for (int n = 0; n < 4; ++n) bfv[n] = *(const short8*)&Vp[(size_t)(n * 16 + il) * S + t];
#pragma unroll
        for (int m = 0; m < 4; ++m)
#pragma unroll
            for (int n = 0; n < 4; ++n)
                acc[m][n] = __builtin_amdgcn_mfma_f32_16x16x32_bf16(af[m], bfv[n], acc[m][n], 0, 0, 0);
    }
    float* Mp = Mpart + ((size_t)slice * 32 + bh) * 4096;
#pragma unroll
    for (int m = 0; m < 4; ++m)
#pragma unroll
        for (int n = 0; n < 4; ++n)
#pragma unroll
            for (int j = 0; j < 4; ++j) {
                int i  = m * 16 + (lane >> 4) * 4 + j;
                int jj = n * 16 + il;
                Mp[i * 64 + jj] = acc[m][n][j];
            }
}

// ---------------------------------------------------------------------------
// K4: out = scale * Q·M via MFMA; folds the 16-slice Mpart reduce.
// ---------------------------------------------------------------------------
__global__ __launch_bounds__(256) void qm_mfma(const ushort* __restrict__ Qb,
                                               const float* __restrict__ Mpart,
                                               float* __restrict__ out) {
    __shared__ ushort Mt[64][72];   // Mt[d][i] = M[i][d], bf16
    const int bh = blockIdx.x, b = bh >> 4, h = bh & 15;
    const int tid = threadIdx.x;
    {
        const int i = tid >> 2, jq = (tid & 3) * 16;
        f32x4 s0 = {}, s1 = {}, s2 = {}, s3 = {};
#pragma unroll
        for (int sl = 0; sl < 16; ++sl) {
            const float* p = Mpart + ((size_t)sl * 32 + bh) * 4096 + i * 64 + jq;
            s0 += *(const f32x4*)(p);
            s1 += *(const f32x4*)(p + 4);
            s2 += *(const f32x4*)(p + 8);
            s3 += *(const f32x4*)(p + 12);
        }
#pragma unroll
        for (int k = 0; k < 4; ++k) {
            Mt[jq + 0  + k][i] = f2bf(s0[k]);
            Mt[jq + 4  + k][i] = f2bf(s1[k]);
            Mt[jq + 8  + k][i] = f2bf(s2[k]);
            Mt[jq + 12 + k][i] = f2bf(s3[k]);
        }
    }
    __syncthreads();
    const int wave = tid >> 6, lane = tid & 63;
    const int sl15 = lane & 15, koct = (lane >> 4) * 8;
    const int s0b = blockIdx.y * 256 + wave * 64;
    f32x4 acc[4][4] = {};
#pragma unroll
    for (int ks = 0; ks < 2; ++ks) {
        short8 af[4], bfv[4];
#pragma unroll
        for (int m = 0; m < 4; ++m) {
            int s = s0b + m * 16 + sl15;
            af[m] = *(const short8*)&Qb[((size_t)bh * S + s) * HD + ks * 32 + koct];
        }
#pragma unroll
        for (int n = 0; n < 4; ++n)
            bfv[n] = *(const short8*)&Mt[n * 16 + sl15][ks * 32 + koct];
#pragma unroll
        for (int m = 0; m < 4; ++m)
#pragma unroll
            for (int n = 0; n < 4; ++n)
                acc[m][n] = __builtin_amdgcn_mfma_f32_16x16x32_bf16(af[m], bfv[n], acc[m][n], 0, 0, 0);
    }
    const float scale = 0.125f * 0.02209708691207961f;  // HD^-0.5 * S^-0.5
#pragma unroll
    for (int m = 0; m < 4; ++m)
#pragma unroll
        for (int n = 0; n < 4; ++n)
#pragma unroll
            for (int j = 0; j < 4; ++j) {
                int s = s0b + m * 16 + (lane >> 4) * 4 + j;
                int d = n * 16 + sl15;
                out[(size_t)(s * B + b) * H + h * 64 + d] = acc[m][n][j] * scale;
            }
}

// ---------------------------------------------------------------------------
extern "C" void kernel_launch(void* const* d_in, const int* in_sizes, int n_in,
                              void* d_out, int out_size, void* d_ws, size_t ws_size,
                              hipStream_t stream) {
    const float* hidden = (const float*)d_in[0];
    const float* W      = (const float*)d_in[1];
    const float* bias   = (const float*)d_in[2];
    float* out = (float*)d_out;

    ushort* Qb    = (ushort*)d_ws;                      //  8 MB  [bh][s][d] bf16
    ushort* Kt    = Qb + 4194304;                       //  8 MB  [bh][d][t] bf16
    ushort* Vraw  = Kt + 4194304;                       //  8 MB  [bh][d][t] bf16 (scan in place)
    float*  csum  = (float*)(Vraw + 4194304);           // 0.5 MB [chunk][col]
    float*  Mpart = csum + 131072;                      //  8 MB  [16][bh][64][64]
    ushort* Abf   = (ushort*)(Mpart + 2097152);         //  8 MB
    ushort* Wbf   = Abf + 4194304;                      //  6 MB
    // total ~46.5 MB of d_ws

    cast_both<<<(N8_A + N8_W + 255) / 256, 256, 0, stream>>>(hidden, W, Abf, Wbf);
    qkv_gemm_mfma<<<dim3(ROWS / 128, THREE_H / 128), 256, 0, stream>>>(Abf, Wbf, bias, Qb, Kt, Vraw);
    vsuf_chunksum<<<512, 256, 0, stream>>>(Vraw, csum);
    vsuf_final<<<512, 256, 0, stream>>>(Vraw, csum);
    kvm_mfma<<<dim3(32, 4), 256, 0, stream>>>(Kt, Vraw, Mpart);
    qm_mfma<<<dim3(32, 8), 256, 0, stream>>>(Qb, Mpart, out);
}

// Round 7
// 91.025 us; speedup vs baseline: 1.0411x; 1.0411x over previous
//
#include <hip/hip_runtime.h>

#define S 2048
#define B 2
#define H 1024
#define NH 16
#define HD 64
#define THREE_H 3072
#define ROWS (S*B)   // 4096

typedef __attribute__((ext_vector_type(8))) short short8;
typedef __attribute__((ext_vector_type(4))) float f32x4;
typedef const __attribute__((address_space(1))) unsigned int* gptr_t;
typedef __attribute__((address_space(3))) unsigned int* lptr_t;

#define N8_A (ROWS * H / 8)        // 524288
#define N8_W (THREE_H * H / 8)     // 393216

__device__ __forceinline__ ushort f2bf(float f) {
    union { float f; unsigned u; } v; v.f = f;
    unsigned r = v.u + 0x7fffu + ((v.u >> 16) & 1u);
    return (ushort)(r >> 16);
}
__device__ __forceinline__ float bf2f(ushort u) {
    union { unsigned u; float f; } v; v.u = ((unsigned)u) << 16;
    return v.f;
}

// ---------------------------------------------------------------------------
// Cast f32 -> bf16 for A and W in one launch
// ---------------------------------------------------------------------------
__global__ void cast_both(const float* __restrict__ A, const float* __restrict__ W,
                          ushort* __restrict__ Ab, ushort* __restrict__ Wb) {
    int i = blockIdx.x * 256 + threadIdx.x;
    const float4* s4;
    ushort* dst;
    if (i < N8_A) { s4 = (const float4*)A; dst = Ab; }
    else if (i < N8_A + N8_W) { s4 = (const float4*)W; dst = Wb; i -= N8_A; }
    else return;
    float4 a = s4[2 * i], b = s4[2 * i + 1];
    short8 o;
    o[0] = f2bf(a.x); o[1] = f2bf(a.y); o[2] = f2bf(a.z); o[3] = f2bf(a.w);
    o[4] = f2bf(b.x); o[5] = f2bf(b.y); o[6] = f2bf(b.z); o[7] = f2bf(b.w);
    *(short8*)(dst + 8 * (size_t)i) = o;
}

// ---------------------------------------------------------------------------
// K1: bf16 MFMA GEMM, BK=64, XOR-swizzled LDS staging (rule #21: linear
// global_load_lds dest + inverse-swizzled SOURCE + swizzled ds_read).
// Epilogue = R4-proven direct scatter (Q,K,V all bf16).
// XCD-aware block swizzle (768 % 8 == 0 -> simple form bijective).
// ---------------------------------------------------------------------------
__global__ __launch_bounds__(256) void qkv_gemm_mfma(const ushort* __restrict__ Abf,
                                                     const ushort* __restrict__ Wbf,
                                                     const float* __restrict__ bias,
                                                     ushort* __restrict__ Qb,
                                                     ushort* __restrict__ Kb,
                                                     ushort* __restrict__ Vraw) {
    __shared__ ushort Abuf[128 * 64];   // 16 KB, rows of 128B, swizzled content
    __shared__ ushort Bbuf[128 * 64];   // 16 KB
    const int tid = threadIdx.x;
    const int wave = tid >> 6, lane = tid & 63;
    const int wr = wave >> 1, wc = wave & 1;

    // XCD swizzle: wgid 0..767, 8 XCDs, 96 blocks per XCD chunk
    const int wgid = blockIdx.y * 32 + blockIdx.x;
    const int swz = (wgid & 7) * 96 + (wgid >> 3);
    const int row0 = (swz & 31) * 128;
    const int col0 = (swz >> 5) * 128;

    f32x4 acc[4][4] = {};

    const int srow = lane >> 3;                     // 0..7 (row within 8-row chunk)
    const int gk = ((lane & 7) ^ srow) * 8;         // inverse-swizzled source k-chunk
    const int il = lane & 15, ko = lane >> 4;

    for (int k0 = 0; k0 < H; k0 += 64) {
#pragma unroll
        for (int p = 0; p < 4; ++p) {
            int row = wave * 32 + p * 8 + srow;
            __builtin_amdgcn_global_load_lds(
                (gptr_t)&Abf[(size_t)(row0 + row) * H + k0 + gk],
                (lptr_t)&Abuf[(wave * 32 + p * 8) * 64 + lane * 8], 16, 0, 0);
            __builtin_amdgcn_global_load_lds(
                (gptr_t)&Wbf[(size_t)(col0 + row) * H + k0 + gk],
                (lptr_t)&Bbuf[(wave * 32 + p * 8) * 64 + lane * 8], 16, 0, 0);
        }
        __syncthreads();

        short8 af[4][2], bfr[4][2];
#pragma unroll
        for (int m = 0; m < 4; ++m) {
            int ar = wr * 64 + m * 16 + il;
            int br = wc * 64 + m * 16 + il;
#pragma unroll
            for (int ks = 0; ks < 2; ++ks) {
                int aslot = (ks * 4 + ko) ^ (ar & 7);
                int bslot = (ks * 4 + ko) ^ (br & 7);
                af[m][ks]  = *(const short8*)&Abuf[ar * 64 + aslot * 8];
                bfr[m][ks] = *(const short8*)&Bbuf[br * 64 + bslot * 8];
            }
        }
#pragma unroll
        for (int ks = 0; ks < 2; ++ks)
#pragma unroll
            for (int m = 0; m < 4; ++m)
#pragma unroll
                for (int n = 0; n < 4; ++n)
                    acc[m][n] = __builtin_amdgcn_mfma_f32_16x16x32_bf16(
                        af[m][ks], bfr[n][ks], acc[m][n], 0, 0, 0);
        __syncthreads();
    }

    // ---- R4-proven scatter epilogue (all outputs bf16) ----
#pragma unroll
    for (int n = 0; n < 4; ++n) {
        int cbase = col0 + wc * 64 + n * 16;     // within one 64-col (h,sel) segment
        int h   = cbase / 192;
        int r3  = cbase % 192;
        int sel = r3 >> 6;                       // 0=q 1=k 2=v, wave-uniform
        int d   = (r3 & 63) + il;
        float bv = bias[cbase + il];
        ushort* dst = (sel == 0) ? Qb : (sel == 1) ? Kb : Vraw;
#pragma unroll
        for (int m = 0; m < 4; ++m) {
            int rowb = row0 + wr * 64 + m * 16 + ko * 4;
#pragma unroll
            for (int j = 0; j < 4; ++j) {
                int r = rowb + j;
                int s = r >> 1, b = r & 1;       // r = s*B + b, B=2
                dst[((size_t)((b * NH + h) * S + s)) * HD + d] = f2bf(acc[m][n][j] + bv);
            }
        }
    }
}

// ---------------------------------------------------------------------------
// Merged: K transpose (blocks 0..1023) + V chunk sums (blocks 1024..1535).
// Independent work after the GEMM -> one launch.
// ---------------------------------------------------------------------------
__global__ __launch_bounds__(256) void ktrans_chunksum(const ushort* __restrict__ Kb,
                                                       ushort* __restrict__ Kt,
                                                       const ushort* __restrict__ Vraw,
                                                       float* __restrict__ csum) {
    __shared__ ushort Ks[64][72];
    const int gb = blockIdx.x;
    const int tid = threadIdx.x;
    if (gb < 1024) {
        const int bh = gb >> 5;
        const int t0 = (gb & 31) * 64;
        {
            const int tt = tid >> 2, part = (tid & 3) * 16;
            const ushort* src = Kb + ((size_t)bh * S + t0 + tt) * HD + part;
            *(short8*)&Ks[tt][part]     = *(const short8*)(src);
            *(short8*)&Ks[tt][part + 8] = *(const short8*)(src + 8);
        }
        __syncthreads();
        {
            const int d = tid >> 2, tq = (tid & 3) * 16;
            ushort tmp[16];
#pragma unroll
            for (int k = 0; k < 16; ++k) tmp[k] = Ks[tq + k][d];
            ushort* dst = Kt + ((size_t)bh * HD + d) * S + t0 + tq;
            short8 o0, o1;
#pragma unroll
            for (int k = 0; k < 8; ++k) { o0[k] = tmp[k]; o1[k] = tmp[8 + k]; }
            *(short8*)dst = o0;
            *(short8*)(dst + 8) = o1;
        }
    } else {
        int idx = (gb - 1024) * 256 + tid;       // chunk*2048 + col
        int col = idx & 2047;                    // bh*64 + d
        int chunk = idx >> 11;                   // 0..63
        const ushort* vp = Vraw + ((size_t)(col >> 6) * S + chunk * 32) * HD + (col & 63);
        float s = 0.f;
#pragma unroll
        for (int t = 0; t < 32; ++t) s += bf2f(vp[(size_t)t * HD]);
        csum[chunk * 2048 + col] = s;
    }
}

// ---------------------------------------------------------------------------
// Suffix-scan finalize: writes Vsuf TRANSPOSED [bh][d][t] bf16.
// ---------------------------------------------------------------------------
__global__ void vsuft_final(const ushort* __restrict__ Vraw, const float* __restrict__ csum,
                            ushort* __restrict__ Vt) {
    int idx = blockIdx.x * 256 + threadIdx.x;
    int col = idx & 2047;
    int chunk = idx >> 11;
    int bh = col >> 6, d = col & 63;
    float acc = 0.f;
    for (int c = chunk + 1; c < 64; ++c) acc += csum[c * 2048 + col];
    const ushort* vp = Vraw + ((size_t)bh * S + chunk * 32) * HD + d;
    ushort buf[32];
#pragma unroll
    for (int tt = 31; tt >= 0; --tt) {
        acc += bf2f(vp[(size_t)tt * HD]);
        buf[tt] = f2bf(acc);
    }
    ushort* op = Vt + ((size_t)bh * HD + d) * S + chunk * 32;
#pragma unroll
    for (int q = 0; q < 4; ++q) {
        short8 o;
#pragma unroll
        for (int k = 0; k < 8; ++k) o[k] = buf[q * 8 + k];
        *(short8*)(op + q * 8) = o;
    }
}

// ---------------------------------------------------------------------------
// K3: M[i][j] = sum_t Kt[i][t]*Vt[j][t] via MFMA. 16 k-slices of 128 t.
// ---------------------------------------------------------------------------
__global__ __launch_bounds__(256) void kvm_mfma(const ushort* __restrict__ Kt,
                                                const ushort* __restrict__ Vt,
                                                float* __restrict__ Mpart) {
    const int bh = blockIdx.x, kb = blockIdx.y;
    const int tid = threadIdx.x, wave = tid >> 6, lane = tid & 63;
    const int slice = kb * 4 + wave;
    const ushort* Kp = Kt + (size_t)bh * HD * S;
    const ushort* Vp = Vt + (size_t)bh * HD * S;
    f32x4 acc[4][4] = {};
    const int il = lane & 15;
    const int tbase = slice * 128 + (lane >> 4) * 8;
#pragma unroll
    for (int ks = 0; ks < 4; ++ks) {
        const int t = tbase + ks * 32;
        short8 af[4], bfv[4];
#pragma unroll
        for (int m = 0; m < 4; ++m) af[m]  = *(const short8*)&Kp[(size_t)(m * 16 + il) * S + t];
#pragma unroll
        for (int n = 0; n < 4; ++n) bfv[n] = *(const short8*)&Vp[(size_t)(n * 16 + il) * S + t];
#pragma unroll
        for (int m = 0; m < 4; ++m)
#pragma unroll
            for (int n = 0; n < 4; ++n)
                acc[m][n] = __builtin_amdgcn_mfma_f32_16x16x32_bf16(af[m], bfv[n], acc[m][n], 0, 0, 0);
    }
    float* Mp = Mpart + ((size_t)slice * 32 + bh) * 4096;
#pragma unroll
    for (int m = 0; m < 4; ++m)
#pragma unroll
        for (int n = 0; n < 4; ++n)
#pragma unroll
            for (int j = 0; j < 4; ++j) {
                int i  = m * 16 + (lane >> 4) * 4 + j;
                int jj = n * 16 + il;
                Mp[i * 64 + jj] = acc[m][n][j];
            }
}

// ---------------------------------------------------------------------------
// K4: out = scale * Q·M via MFMA; folds the 16-slice Mpart reduce.
// ---------------------------------------------------------------------------
__global__ __launch_bounds__(256) void qm_mfma(const ushort* __restrict__ Qb,
                                               const float* __restrict__ Mpart,
                                               float* __restrict__ out) {
    __shared__ ushort Mt[64][72];   // Mt[d][i] = M[i][d], bf16
    const int bh = blockIdx.x, b = bh >> 4, h = bh & 15;
    const int tid = threadIdx.x;
    {
        const int i = tid >> 2, jq = (tid & 3) * 16;
        f32x4 s0 = {}, s1 = {}, s2 = {}, s3 = {};
#pragma unroll
        for (int sl = 0; sl < 16; ++sl) {
            const float* p = Mpart + ((size_t)sl * 32 + bh) * 4096 + i * 64 + jq;
            s0 += *(const f32x4*)(p);
            s1 += *(const f32x4*)(p + 4);
            s2 += *(const f32x4*)(p + 8);
            s3 += *(const f32x4*)(p + 12);
        }
#pragma unroll
        for (int k = 0; k < 4; ++k) {
            Mt[jq + 0  + k][i] = f2bf(s0[k]);
            Mt[jq + 4  + k][i] = f2bf(s1[k]);
            Mt[jq + 8  + k][i] = f2bf(s2[k]);
            Mt[jq + 12 + k][i] = f2bf(s3[k]);
        }
    }
    __syncthreads();
    const int wave = tid >> 6, lane = tid & 63;
    const int sl15 = lane & 15, koct = (lane >> 4) * 8;
    const int s0b = blockIdx.y * 256 + wave * 64;
    f32x4 acc[4][4] = {};
#pragma unroll
    for (int ks = 0; ks < 2; ++ks) {
        short8 af[4], bfv[4];
#pragma unroll
        for (int m = 0; m < 4; ++m) {
            int s = s0b + m * 16 + sl15;
            af[m] = *(const short8*)&Qb[((size_t)bh * S + s) * HD + ks * 32 + koct];
        }
#pragma unroll
        for (int n = 0; n < 4; ++n)
            bfv[n] = *(const short8*)&Mt[n * 16 + sl15][ks * 32 + koct];
#pragma unroll
        for (int m = 0; m < 4; ++m)
#pragma unroll
            for (int n = 0; n < 4; ++n)
                acc[m][n] = __builtin_amdgcn_mfma_f32_16x16x32_bf16(af[m], bfv[n], acc[m][n], 0, 0, 0);
    }
    const float scale = 0.125f * 0.02209708691207961f;  // HD^-0.5 * S^-0.5
#pragma unroll
    for (int m = 0; m < 4; ++m)
#pragma unroll
        for (int n = 0; n < 4; ++n)
#pragma unroll
            for (int j = 0; j < 4; ++j) {
                int s = s0b + m * 16 + (lane >> 4) * 4 + j;
                int d = n * 16 + sl15;
                out[(size_t)(s * B + b) * H + h * 64 + d] = acc[m][n][j] * scale;
            }
}

// ---------------------------------------------------------------------------
extern "C" void kernel_launch(void* const* d_in, const int* in_sizes, int n_in,
                              void* d_out, int out_size, void* d_ws, size_t ws_size,
                              hipStream_t stream) {
    const float* hidden = (const float*)d_in[0];
    const float* W      = (const float*)d_in[1];
    const float* bias   = (const float*)d_in[2];
    float* out = (float*)d_out;

    ushort* Qb    = (ushort*)d_ws;                      //  8 MB  [bh][s][d]
    ushort* Kb    = Qb + 4194304;                       //  8 MB  [bh][t][d]
    ushort* Kt    = Kb + 4194304;                       //  8 MB  [bh][d][t]
    ushort* Vraw  = Kt + 4194304;                       //  8 MB  [bh][t][d]
    ushort* Vt    = Vraw + 4194304;                     //  8 MB  [bh][d][t]
    float*  csum  = (float*)(Vt + 4194304);             // 0.5 MB [chunk][col]
    float*  Mpart = csum + 131072;                      //  8 MB  [16][bh][64][64]
    ushort* Abf   = (ushort*)(Mpart + 2097152);         //  8 MB
    ushort* Wbf   = Abf + 4194304;                      //  6 MB
    // total ~62.5 MB of d_ws

    cast_both<<<(N8_A + N8_W + 255) / 256, 256, 0, stream>>>(hidden, W, Abf, Wbf);
    qkv_gemm_mfma<<<dim3(32, 24), 256, 0, stream>>>(Abf, Wbf, bias, Qb, Kb, Vraw);
    ktrans_chunksum<<<1536, 256, 0, stream>>>(Kb, Kt, Vraw, csum);
    vsuft_final<<<512, 256, 0, stream>>>(Vraw, csum, Vt);
    kvm_mfma<<<dim3(32, 4), 256, 0, stream>>>(Kt, Vt, Mpart);
    qm_mfma<<<dim3(32, 8), 256, 0, stream>>>(Qb, Mpart, out);
}

// Round 8
// 78.043 us; speedup vs baseline: 1.2143x; 1.1664x over previous
//
#include <hip/hip_runtime.h>

#define S 2048
#define B 2
#define H 1024
#define NH 16
#define HD 64
#define THREE_H 3072
#define ROWS (S*B)   // 4096

typedef __attribute__((ext_vector_type(8))) short short8;
typedef __attribute__((ext_vector_type(4))) float f32x4;
typedef const __attribute__((address_space(1))) unsigned int* gptr_t;
typedef __attribute__((address_space(3))) unsigned int* lptr_t;

#define N8_A (ROWS * H / 8)        // 524288
#define N8_W (THREE_H * H / 8)     // 393216

__device__ __forceinline__ ushort f2bf(float f) {
    union { float f; unsigned u; } v; v.f = f;
    unsigned r = v.u + 0x7fffu + ((v.u >> 16) & 1u);
    return (ushort)(r >> 16);
}
__device__ __forceinline__ float bf2f(ushort u) {
    union { unsigned u; float f; } v; v.u = ((unsigned)u) << 16;
    return v.f;
}

// ---------------------------------------------------------------------------
// Cast f32 -> bf16 for A and W in one launch
// ---------------------------------------------------------------------------
__global__ void cast_both(const float* __restrict__ A, const float* __restrict__ W,
                          ushort* __restrict__ Ab, ushort* __restrict__ Wb) {
    int i = blockIdx.x * 256 + threadIdx.x;
    const float4* s4;
    ushort* dst;
    if (i < N8_A) { s4 = (const float4*)A; dst = Ab; }
    else if (i < N8_A + N8_W) { s4 = (const float4*)W; dst = Wb; i -= N8_A; }
    else return;
    float4 a = s4[2 * i], b = s4[2 * i + 1];
    short8 o;
    o[0] = f2bf(a.x); o[1] = f2bf(a.y); o[2] = f2bf(a.z); o[3] = f2bf(a.w);
    o[4] = f2bf(b.x); o[5] = f2bf(b.y); o[6] = f2bf(b.z); o[7] = f2bf(b.w);
    *(short8*)(dst + 8 * (size_t)i) = o;
}

// ---------------------------------------------------------------------------
// K1: bf16 MFMA GEMM. R4 structure (BK=32, 16KB LDS, natural block order,
// direct scatter epilogue) + XOR-swizzled staging (rule #21: linear LDS dest,
// inverse-swizzled SOURCE octet, swizzled ds_read slot) -> 2-way (free) banks.
// ---------------------------------------------------------------------------
__global__ __launch_bounds__(256) void qkv_gemm_mfma(const ushort* __restrict__ Abf,
                                                     const ushort* __restrict__ Wbf,
                                                     const float* __restrict__ bias,
                                                     ushort* __restrict__ Qb,
                                                     ushort* __restrict__ Kb,
                                                     ushort* __restrict__ Vraw) {
    __shared__ ushort Abuf[128 * 32];   // 8 KB
    __shared__ ushort Bbuf[128 * 32];   // 8 KB
    const int tid = threadIdx.x;
    const int wave = tid >> 6, lane = tid & 63;
    const int wr = wave >> 1, wc = wave & 1;
    const int row0 = blockIdx.x * 128;
    const int col0 = blockIdx.y * 128;

    f32x4 acc[4][4] = {};

    const int lrow = lane >> 2;                          // 0..15 row in 16-row chunk
    const int gk = ((lane & 3) ^ (lrow & 3)) * 8;        // inverse-swizzled src octet
    const int il = lane & 15, ko = lane >> 4;

    for (int k0 = 0; k0 < H; k0 += 32) {
#pragma unroll
        for (int p = 0; p < 2; ++p) {
            int c = wave * 2 + p;
            int row = c * 16 + lrow;
            __builtin_amdgcn_global_load_lds(
                (gptr_t)&Abf[(size_t)(row0 + row) * H + k0 + gk],
                (lptr_t)&Abuf[c * 512 + lane * 8], 16, 0, 0);
            __builtin_amdgcn_global_load_lds(
                (gptr_t)&Wbf[(size_t)(col0 + row) * H + k0 + gk],
                (lptr_t)&Bbuf[c * 512 + lane * 8], 16, 0, 0);
        }
        __syncthreads();

        short8 af[4], bfr[4];
#pragma unroll
        for (int m = 0; m < 4; ++m) {
            int ar = wr * 64 + m * 16 + il;
            int br = wc * 64 + m * 16 + il;
            af[m]  = *(const short8*)&Abuf[ar * 32 + (ko ^ (ar & 3)) * 8];
            bfr[m] = *(const short8*)&Bbuf[br * 32 + (ko ^ (br & 3)) * 8];
        }
#pragma unroll
        for (int m = 0; m < 4; ++m)
#pragma unroll
            for (int n = 0; n < 4; ++n)
                acc[m][n] = __builtin_amdgcn_mfma_f32_16x16x32_bf16(af[m], bfr[n], acc[m][n], 0, 0, 0);
        __syncthreads();
    }

    // ---- direct scatter epilogue (all outputs bf16, [bh][s|t][d]) ----
#pragma unroll
    for (int n = 0; n < 4; ++n) {
        int cbase = col0 + wc * 64 + n * 16;     // within one 64-col (h,sel) segment
        int h   = cbase / 192;
        int r3  = cbase % 192;
        int sel = r3 >> 6;                       // 0=q 1=k 2=v, wave-uniform
        int d   = (r3 & 63) + il;
        float bv = bias[cbase + il];
        ushort* dst = (sel == 0) ? Qb : (sel == 1) ? Kb : Vraw;
#pragma unroll
        for (int m = 0; m < 4; ++m) {
            int rowb = row0 + wr * 64 + m * 16 + ko * 4;
#pragma unroll
            for (int j = 0; j < 4; ++j) {
                int r = rowb + j;
                int s = r >> 1, b = r & 1;       // r = s*B + b, B=2
                dst[((size_t)((b * NH + h) * S + s)) * HD + d] = f2bf(acc[m][n][j] + bv);
            }
        }
    }
}

// ---------------------------------------------------------------------------
// Merged: K transpose (blocks 0..1023) + V chunk sums (blocks 1024..1535).
// ---------------------------------------------------------------------------
__global__ __launch_bounds__(256) void ktrans_chunksum(const ushort* __restrict__ Kb,
                                                       ushort* __restrict__ Kt,
                                                       const ushort* __restrict__ Vraw,
                                                       float* __restrict__ csum) {
    __shared__ ushort Ks[64][72];
    const int gb = blockIdx.x;
    const int tid = threadIdx.x;
    if (gb < 1024) {
        const int bh = gb >> 5;
        const int t0 = (gb & 31) * 64;
        {
            const int tt = tid >> 2, part = (tid & 3) * 16;
            const ushort* src = Kb + ((size_t)bh * S + t0 + tt) * HD + part;
            *(short8*)&Ks[tt][part]     = *(const short8*)(src);
            *(short8*)&Ks[tt][part + 8] = *(const short8*)(src + 8);
        }
        __syncthreads();
        {
            const int d = tid >> 2, tq = (tid & 3) * 16;
            ushort tmp[16];
#pragma unroll
            for (int k = 0; k < 16; ++k) tmp[k] = Ks[tq + k][d];
            ushort* dst = Kt + ((size_t)bh * HD + d) * S + t0 + tq;
            short8 o0, o1;
#pragma unroll
            for (int k = 0; k < 8; ++k) { o0[k] = tmp[k]; o1[k] = tmp[8 + k]; }
            *(short8*)dst = o0;
            *(short8*)(dst + 8) = o1;
        }
    } else {
        int idx = (gb - 1024) * 256 + tid;       // chunk*2048 + col
        int col = idx & 2047;                    // bh*64 + d
        int chunk = idx >> 11;                   // 0..63
        const ushort* vp = Vraw + ((size_t)(col >> 6) * S + chunk * 32) * HD + (col & 63);
        float s = 0.f;
#pragma unroll
        for (int t = 0; t < 32; ++t) s += bf2f(vp[(size_t)t * HD]);
        csum[chunk * 2048 + col] = s;
    }
}

// ---------------------------------------------------------------------------
// Suffix-scan finalize: writes Vsuf TRANSPOSED [bh][d][t] bf16.
// ---------------------------------------------------------------------------
__global__ void vsuft_final(const ushort* __restrict__ Vraw, const float* __restrict__ csum,
                            ushort* __restrict__ Vt) {
    int idx = blockIdx.x * 256 + threadIdx.x;
    int col = idx & 2047;
    int chunk = idx >> 11;
    int bh = col >> 6, d = col & 63;
    float acc = 0.f;
    for (int c = chunk + 1; c < 64; ++c) acc += csum[c * 2048 + col];
    const ushort* vp = Vraw + ((size_t)bh * S + chunk * 32) * HD + d;
    ushort buf[32];
#pragma unroll
    for (int tt = 31; tt >= 0; --tt) {
        acc += bf2f(vp[(size_t)tt * HD]);
        buf[tt] = f2bf(acc);
    }
    ushort* op = Vt + ((size_t)bh * HD + d) * S + chunk * 32;
#pragma unroll
    for (int q = 0; q < 4; ++q) {
        short8 o;
#pragma unroll
        for (int k = 0; k < 8; ++k) o[k] = buf[q * 8 + k];
        *(short8*)(op + q * 8) = o;
    }
}

// ---------------------------------------------------------------------------
// K3: M[i][j] = sum_t Kt[i][t]*Vt[j][t] via MFMA. Each wave does one 512-t
// slice; 4 waves reduced in-block via LDS -> Mpart has 4 slices (was 16).
// ---------------------------------------------------------------------------
__global__ __launch_bounds__(256) void kvm_mfma(const ushort* __restrict__ Kt,
                                                const ushort* __restrict__ Vt,
                                                float* __restrict__ Mpart) {
    __shared__ float red[2][4096];   // 32 KB
    const int bh = blockIdx.x, kb = blockIdx.y;
    const int tid = threadIdx.x, wave = tid >> 6, lane = tid & 63;
    const int slice = kb * 4 + wave;
    const ushort* Kp = Kt + (size_t)bh * HD * S;
    const ushort* Vp = Vt + (size_t)bh * HD * S;
    f32x4 acc[4][4] = {};
    const int il = lane & 15, g = lane >> 4;
    const int tbase = slice * 128 + g * 8;
#pragma unroll
    for (int ks = 0; ks < 4; ++ks) {
        const int t = tbase + ks * 32;
        short8 af[4], bfv[4];
#pragma unroll
        for (int m = 0; m < 4; ++m) af[m]  = *(const short8*)&Kp[(size_t)(m * 16 + il) * S + t];
#pragma unroll
        for (int n = 0; n < 4; ++n) bfv[n] = *(const short8*)&Vp[(size_t)(n * 16 + il) * S + t];
#pragma unroll
        for (int m = 0; m < 4; ++m)
#pragma unroll
            for (int n = 0; n < 4; ++n)
                acc[m][n] = __builtin_amdgcn_mfma_f32_16x16x32_bf16(af[m], bfv[n], acc[m][n], 0, 0, 0);
    }
    // cross-wave reduce: waves {1,3} dump, {0,2} add; wave2 dump, wave0 add.
#define DUMP(dstbuf)                                                        \
    { float* _d = (dstbuf);                                                 \
      _Pragma("unroll") for (int m = 0; m < 4; ++m)                         \
      _Pragma("unroll") for (int n = 0; n < 4; ++n)                         \
      _Pragma("unroll") for (int j = 0; j < 4; ++j)                         \
          _d[(m * 16 + g * 4 + j) * 64 + n * 16 + il] = acc[m][n][j]; }
#define ADDIN(srcbuf)                                                       \
    { const float* _s = (srcbuf);                                           \
      _Pragma("unroll") for (int m = 0; m < 4; ++m)                         \
      _Pragma("unroll") for (int n = 0; n < 4; ++n)                         \
      _Pragma("unroll") for (int j = 0; j < 4; ++j)                         \
          acc[m][n][j] += _s[(m * 16 + g * 4 + j) * 64 + n * 16 + il]; }
    if (wave == 1) DUMP(red[0]);
    if (wave == 3) DUMP(red[1]);
    __syncthreads();
    if (wave == 0) ADDIN(red[0]);
    if (wave == 2) ADDIN(red[1]);
    __syncthreads();
    if (wave == 2) DUMP(red[0]);
    __syncthreads();
    if (wave == 0) {
        ADDIN(red[0]);
        float* Mp = Mpart + ((size_t)kb * 32 + bh) * 4096;
#pragma unroll
        for (int m = 0; m < 4; ++m)
#pragma unroll
            for (int n = 0; n < 4; ++n)
#pragma unroll
                for (int j = 0; j < 4; ++j)
                    Mp[(m * 16 + g * 4 + j) * 64 + n * 16 + il] = acc[m][n][j];
    }
#undef DUMP
#undef ADDIN
}

// ---------------------------------------------------------------------------
// K4: out = scale * Q·M via MFMA; folds the 4-slice Mpart reduce.
// ---------------------------------------------------------------------------
__global__ __launch_bounds__(256) void qm_mfma(const ushort* __restrict__ Qb,
                                               const float* __restrict__ Mpart,
                                               float* __restrict__ out) {
    __shared__ ushort Mt[64][72];   // Mt[d][i] = M[i][d], bf16
    const int bh = blockIdx.x, b = bh >> 4, h = bh & 15;
    const int tid = threadIdx.x;
    {
        const int i = tid >> 2, jq = (tid & 3) * 16;
        f32x4 s0 = {}, s1 = {}, s2 = {}, s3 = {};
#pragma unroll
        for (int sl = 0; sl < 4; ++sl) {
            const float* p = Mpart + ((size_t)sl * 32 + bh) * 4096 + i * 64 + jq;
            s0 += *(const f32x4*)(p);
            s1 += *(const f32x4*)(p + 4);
            s2 += *(const f32x4*)(p + 8);
            s3 += *(const f32x4*)(p + 12);
        }
#pragma unroll
        for (int k = 0; k < 4; ++k) {
            Mt[jq + 0  + k][i] = f2bf(s0[k]);
            Mt[jq + 4  + k][i] = f2bf(s1[k]);
            Mt[jq + 8  + k][i] = f2bf(s2[k]);
            Mt[jq + 12 + k][i] = f2bf(s3[k]);
        }
    }
    __syncthreads();
    const int wave = tid >> 6, lane = tid & 63;
    const int sl15 = lane & 15, koct = (lane >> 4) * 8;
    const int s0b = blockIdx.y * 256 + wave * 64;
    f32x4 acc[4][4] = {};
#pragma unroll
    for (int ks = 0; ks < 2; ++ks) {
        short8 af[4], bfv[4];
#pragma unroll
        for (int m = 0; m < 4; ++m) {
            int s = s0b + m * 16 + sl15;
            af[m] = *(const short8*)&Qb[((size_t)bh * S + s) * HD + ks * 32 + koct];
        }
#pragma unroll
        for (int n = 0; n < 4; ++n)
            bfv[n] = *(const short8*)&Mt[n * 16 + sl15][ks * 32 + koct];
#pragma unroll
        for (int m = 0; m < 4; ++m)
#pragma unroll
            for (int n = 0; n < 4; ++n)
                acc[m][n] = __builtin_amdgcn_mfma_f32_16x16x32_bf16(af[m], bfv[n], acc[m][n], 0, 0, 0);
    }
    const float scale = 0.125f * 0.02209708691207961f;  // HD^-0.5 * S^-0.5
#pragma unroll
    for (int m = 0; m < 4; ++m)
#pragma unroll
        for (int n = 0; n < 4; ++n)
#pragma unroll
            for (int j = 0; j < 4; ++j) {
                int s = s0b + m * 16 + (lane >> 4) * 4 + j;
                int d = n * 16 + sl15;
                out[(size_t)(s * B + b) * H + h * 64 + d] = acc[m][n][j] * scale;
            }
}

// ---------------------------------------------------------------------------
extern "C" void kernel_launch(void* const* d_in, const int* in_sizes, int n_in,
                              void* d_out, int out_size, void* d_ws, size_t ws_size,
                              hipStream_t stream) {
    const float* hidden = (const float*)d_in[0];
    const float* W      = (const float*)d_in[1];
    const float* bias   = (const float*)d_in[2];
    float* out = (float*)d_out;

    ushort* Qb    = (ushort*)d_ws;                      //  8 MB  [bh][s][d]
    ushort* Kb    = Qb + 4194304;                       //  8 MB  [bh][t][d]
    ushort* Kt    = Kb + 4194304;                       //  8 MB  [bh][d][t]
    ushort* Vraw  = Kt + 4194304;                       //  8 MB  [bh][t][d]
    ushort* Vt    = Vraw + 4194304;                     //  8 MB  [bh][d][t]
    float*  csum  = (float*)(Vt + 4194304);             // 0.5 MB [chunk][col]
    float*  Mpart = csum + 131072;                      //  2 MB  [4][bh][64][64]
    ushort* Abf   = (ushort*)(Mpart + 524288);          //  8 MB
    ushort* Wbf   = Abf + 4194304;                      //  6 MB
    // total ~56.5 MB of d_ws

    cast_both<<<(N8_A + N8_W + 255) / 256, 256, 0, stream>>>(hidden, W, Abf, Wbf);
    qkv_gemm_mfma<<<dim3(ROWS / 128, THREE_H / 128), 256, 0, stream>>>(Abf, Wbf, bias, Qb, Kb, Vraw);
    ktrans_chunksum<<<1536, 256, 0, stream>>>(Kb, Kt, Vraw, csum);
    vsuft_final<<<512, 256, 0, stream>>>(Vraw, csum, Vt);
    kvm_mfma<<<dim3(32, 4), 256, 0, stream>>>(Kt, Vt, Mpart);
    qm_mfma<<<dim3(32, 8), 256, 0, stream>>>(Qb, Mpart, out);
}

// Round 9
// 71.415 us; speedup vs baseline: 1.3270x; 1.0928x over previous
//
#include <hip/hip_runtime.h>

#define S 2048
#define B 2
#define H 1024
#define NH 16
#define HD 64
#define THREE_H 3072
#define ROWS (S*B)   // 4096

typedef __attribute__((ext_vector_type(8))) short short8;
typedef __attribute__((ext_vector_type(4))) float f32x4;
typedef const __attribute__((address_space(1))) unsigned int* gptr_t;
typedef __attribute__((address_space(3))) unsigned int* lptr_t;

#define N8_A (ROWS * H / 8)        // 524288
#define N8_W (THREE_H * H / 8)     // 393216

__device__ __forceinline__ ushort f2bf(float f) {
    union { float f; unsigned u; } v; v.f = f;
    unsigned r = v.u + 0x7fffu + ((v.u >> 16) & 1u);
    return (ushort)(r >> 16);
}
__device__ __forceinline__ float bf2f(ushort u) {
    union { unsigned u; float f; } v; v.u = ((unsigned)u) << 16;
    return v.f;
}

// ---------------------------------------------------------------------------
// Cast f32 -> bf16 for A and W in one launch
// ---------------------------------------------------------------------------
__global__ void cast_both(const float* __restrict__ A, const float* __restrict__ W,
                          ushort* __restrict__ Ab, ushort* __restrict__ Wb) {
    int i = blockIdx.x * 256 + threadIdx.x;
    const float4* s4;
    ushort* dst;
    if (i < N8_A) { s4 = (const float4*)A; dst = Ab; }
    else if (i < N8_A + N8_W) { s4 = (const float4*)W; dst = Wb; i -= N8_A; }
    else return;
    float4 a = s4[2 * i], b = s4[2 * i + 1];
    short8 o;
    o[0] = f2bf(a.x); o[1] = f2bf(a.y); o[2] = f2bf(a.z); o[3] = f2bf(a.w);
    o[4] = f2bf(b.x); o[5] = f2bf(b.y); o[6] = f2bf(b.z); o[7] = f2bf(b.w);
    *(short8*)(dst + 8 * (size_t)i) = o;
}

// ---------------------------------------------------------------------------
// K1: bf16 MFMA GEMM (R8-proven core: BK=32, XOR-swizzled staging, natural
// block order). Epilogue: Q -> [bh][s][d] scatter; K,V -> [bh][d][t] DIRECT
// transposed write via packed uint stores (acc j=0/2 are consecutive t, b=0;
// j=1/3 consecutive t, b=1). Each 64B line fully written within the block.
// ---------------------------------------------------------------------------
__global__ __launch_bounds__(256) void qkv_gemm_mfma(const ushort* __restrict__ Abf,
                                                     const ushort* __restrict__ Wbf,
                                                     const float* __restrict__ bias,
                                                     ushort* __restrict__ Qb,
                                                     ushort* __restrict__ Ktd,
                                                     ushort* __restrict__ Vtd) {
    __shared__ ushort Abuf[128 * 32];   // 8 KB
    __shared__ ushort Bbuf[128 * 32];   // 8 KB
    const int tid = threadIdx.x;
    const int wave = tid >> 6, lane = tid & 63;
    const int wr = wave >> 1, wc = wave & 1;
    const int row0 = blockIdx.x * 128;
    const int col0 = blockIdx.y * 128;

    f32x4 acc[4][4] = {};

    const int lrow = lane >> 2;                          // 0..15 row in 16-row chunk
    const int gk = ((lane & 3) ^ (lrow & 3)) * 8;        // inverse-swizzled src octet
    const int il = lane & 15, ko = lane >> 4;

    for (int k0 = 0; k0 < H; k0 += 32) {
#pragma unroll
        for (int p = 0; p < 2; ++p) {
            int c = wave * 2 + p;
            int row = c * 16 + lrow;
            __builtin_amdgcn_global_load_lds(
                (gptr_t)&Abf[(size_t)(row0 + row) * H + k0 + gk],
                (lptr_t)&Abuf[c * 512 + lane * 8], 16, 0, 0);
            __builtin_amdgcn_global_load_lds(
                (gptr_t)&Wbf[(size_t)(col0 + row) * H + k0 + gk],
                (lptr_t)&Bbuf[c * 512 + lane * 8], 16, 0, 0);
        }
        __syncthreads();

        short8 af[4], bfr[4];
#pragma unroll
        for (int m = 0; m < 4; ++m) {
            int ar = wr * 64 + m * 16 + il;
            int br = wc * 64 + m * 16 + il;
            af[m]  = *(const short8*)&Abuf[ar * 32 + (ko ^ (ar & 3)) * 8];
            bfr[m] = *(const short8*)&Bbuf[br * 32 + (ko ^ (br & 3)) * 8];
        }
#pragma unroll
        for (int m = 0; m < 4; ++m)
#pragma unroll
            for (int n = 0; n < 4; ++n)
                acc[m][n] = __builtin_amdgcn_mfma_f32_16x16x32_bf16(af[m], bfr[n], acc[m][n], 0, 0, 0);
        __syncthreads();
    }

    // ---- epilogue ----
#pragma unroll
    for (int n = 0; n < 4; ++n) {
        int cbase = col0 + wc * 64 + n * 16;     // within one 64-col (h,sel) segment
        int h   = cbase / 192;
        int r3  = cbase % 192;
        int sel = r3 >> 6;                       // 0=q 1=k 2=v, wave-uniform
        int d   = (r3 & 63) + il;
        float bv = bias[cbase + il];
        if (sel == 0) {
#pragma unroll
            for (int m = 0; m < 4; ++m) {
                int rowb = row0 + wr * 64 + m * 16 + ko * 4;
#pragma unroll
                for (int j = 0; j < 4; ++j) {
                    int r = rowb + j;
                    int s = r >> 1, b = r & 1;   // r = s*B + b, B=2
                    Qb[((size_t)((b * NH + h) * S + s)) * HD + d] = f2bf(acc[m][n][j] + bv);
                }
            }
        } else {
            ushort* dst = (sel == 1) ? Ktd : Vtd;
            const size_t ro0 = ((size_t)(h)      * HD + d) * S;   // b=0 row
            const size_t ro1 = ((size_t)(NH + h) * HD + d) * S;   // b=1 row
#pragma unroll
            for (int m = 0; m < 4; ++m) {
                int t0 = (row0 + wr * 64 + m * 16 + ko * 4) >> 1;  // even
                uint lo = (uint)f2bf(acc[m][n][0] + bv) |
                          ((uint)f2bf(acc[m][n][2] + bv) << 16);   // t0, t0+1 (b=0)
                uint hi = (uint)f2bf(acc[m][n][1] + bv) |
                          ((uint)f2bf(acc[m][n][3] + bv) << 16);   // t0, t0+1 (b=1)
                *(uint*)&dst[ro0 + t0] = lo;
                *(uint*)&dst[ro1 + t0] = hi;
            }
        }
    }
}

// ---------------------------------------------------------------------------
// V suffix-scan, one wave per (bh,d) row of 2048 t, in place on Vtd.
// lane owns 32 consecutive t; shfl-doubling suffix scan of lane sums.
// ---------------------------------------------------------------------------
__global__ __launch_bounds__(256) void vscan(ushort* __restrict__ Vtd) {
    const int row = blockIdx.x * 4 + (threadIdx.x >> 6);  // 0..2047 = bh*64+d
    const int lane = threadIdx.x & 63;
    ushort* vp = Vtd + (size_t)row * S + lane * 32;
    float v[32];
#pragma unroll
    for (int q = 0; q < 4; ++q) {
        short8 x = *(const short8*)(vp + q * 8);
#pragma unroll
        for (int k = 0; k < 8; ++k) v[q * 8 + k] = bf2f((ushort)x[k]);
    }
    float sum = 0.f;
#pragma unroll
    for (int k = 0; k < 32; ++k) sum += v[k];
    // inclusive suffix of lane sums via doubling
    float t = sum;
#pragma unroll
    for (int off = 1; off < 64; off <<= 1) {
        float o = __shfl_down(t, off, 64);
        if (lane + off < 64) t += o;
    }
    float acc = t - sum;   // exclusive suffix (sum of lanes > lane)
#pragma unroll
    for (int k = 31; k >= 0; --k) { acc += v[k]; v[k] = acc; }
#pragma unroll
    for (int q = 0; q < 4; ++q) {
        short8 o;
#pragma unroll
        for (int k = 0; k < 8; ++k) o[k] = f2bf(v[q * 8 + k]);
        *(short8*)(vp + q * 8) = o;
    }
}

// ---------------------------------------------------------------------------
// K3: M[i][j] = sum_t Ktd[i][t]*Vtd[j][t] via MFMA. Each wave one 512-t
// slice; cross-wave LDS reduce -> Mpart has 4 slices.
// ---------------------------------------------------------------------------
__global__ __launch_bounds__(256) void kvm_mfma(const ushort* __restrict__ Kt,
                                                const ushort* __restrict__ Vt,
                                                float* __restrict__ Mpart) {
    __shared__ float red[2][4096];   // 32 KB
    const int bh = blockIdx.x, kb = blockIdx.y;
    const int tid = threadIdx.x, wave = tid >> 6, lane = tid & 63;
    const int slice = kb * 4 + wave;
    const ushort* Kp = Kt + (size_t)bh * HD * S;
    const ushort* Vp = Vt + (size_t)bh * HD * S;
    f32x4 acc[4][4] = {};
    const int il = lane & 15, g = lane >> 4;
    const int tbase = slice * 128 + g * 8;
#pragma unroll
    for (int ks = 0; ks < 4; ++ks) {
        const int t = tbase + ks * 32;
        short8 af[4], bfv[4];
#pragma unroll
        for (int m = 0; m < 4; ++m) af[m]  = *(const short8*)&Kp[(size_t)(m * 16 + il) * S + t];
#pragma unroll
        for (int n = 0; n < 4; ++n) bfv[n] = *(const short8*)&Vp[(size_t)(n * 16 + il) * S + t];
#pragma unroll
        for (int m = 0; m < 4; ++m)
#pragma unroll
            for (int n = 0; n < 4; ++n)
                acc[m][n] = __builtin_amdgcn_mfma_f32_16x16x32_bf16(af[m], bfv[n], acc[m][n], 0, 0, 0);
    }
#define DUMP(dstbuf)                                                        \
    { float* _d = (dstbuf);                                                 \
      _Pragma("unroll") for (int m = 0; m < 4; ++m)                         \
      _Pragma("unroll") for (int n = 0; n < 4; ++n)                         \
      _Pragma("unroll") for (int j = 0; j < 4; ++j)                         \
          _d[(m * 16 + g * 4 + j) * 64 + n * 16 + il] = acc[m][n][j]; }
#define ADDIN(srcbuf)                                                       \
    { const float* _s = (srcbuf);                                           \
      _Pragma("unroll") for (int m = 0; m < 4; ++m)                         \
      _Pragma("unroll") for (int n = 0; n < 4; ++n)                         \
      _Pragma("unroll") for (int j = 0; j < 4; ++j)                         \
          acc[m][n][j] += _s[(m * 16 + g * 4 + j) * 64 + n * 16 + il]; }
    if (wave == 1) DUMP(red[0]);
    if (wave == 3) DUMP(red[1]);
    __syncthreads();
    if (wave == 0) ADDIN(red[0]);
    if (wave == 2) ADDIN(red[1]);
    __syncthreads();
    if (wave == 2) DUMP(red[0]);
    __syncthreads();
    if (wave == 0) {
        ADDIN(red[0]);
        float* Mp = Mpart + ((size_t)kb * 32 + bh) * 4096;
#pragma unroll
        for (int m = 0; m < 4; ++m)
#pragma unroll
            for (int n = 0; n < 4; ++n)
#pragma unroll
                for (int j = 0; j < 4; ++j)
                    Mp[(m * 16 + g * 4 + j) * 64 + n * 16 + il] = acc[m][n][j];
    }
#undef DUMP
#undef ADDIN
}

// ---------------------------------------------------------------------------
// K4: out = scale * Q·M via MFMA; folds the 4-slice Mpart reduce.
// ---------------------------------------------------------------------------
__global__ __launch_bounds__(256) void qm_mfma(const ushort* __restrict__ Qb,
                                               const float* __restrict__ Mpart,
                                               float* __restrict__ out) {
    __shared__ ushort Mt[64][72];   // Mt[d][i] = M[i][d], bf16
    const int bh = blockIdx.x, b = bh >> 4, h = bh & 15;
    const int tid = threadIdx.x;
    {
        const int i = tid >> 2, jq = (tid & 3) * 16;
        f32x4 s0 = {}, s1 = {}, s2 = {}, s3 = {};
#pragma unroll
        for (int sl = 0; sl < 4; ++sl) {
            const float* p = Mpart + ((size_t)sl * 32 + bh) * 4096 + i * 64 + jq;
            s0 += *(const f32x4*)(p);
            s1 += *(const f32x4*)(p + 4);
            s2 += *(const f32x4*)(p + 8);
            s3 += *(const f32x4*)(p + 12);
        }
#pragma unroll
        for (int k = 0; k < 4; ++k) {
            Mt[jq + 0  + k][i] = f2bf(s0[k]);
            Mt[jq + 4  + k][i] = f2bf(s1[k]);
            Mt[jq + 8  + k][i] = f2bf(s2[k]);
            Mt[jq + 12 + k][i] = f2bf(s3[k]);
        }
    }
    __syncthreads();
    const int wave = tid >> 6, lane = tid & 63;
    const int sl15 = lane & 15, koct = (lane >> 4) * 8;
    const int s0b = blockIdx.y * 256 + wave * 64;
    f32x4 acc[4][4] = {};
#pragma unroll
    for (int ks = 0; ks < 2; ++ks) {
        short8 af[4], bfv[4];
#pragma unroll
        for (int m = 0; m < 4; ++m) {
            int s = s0b + m * 16 + sl15;
            af[m] = *(const short8*)&Qb[((size_t)bh * S + s) * HD + ks * 32 + koct];
        }
#pragma unroll
        for (int n = 0; n < 4; ++n)
            bfv[n] = *(const short8*)&Mt[n * 16 + sl15][ks * 32 + koct];
#pragma unroll
        for (int m = 0; m < 4; ++m)
#pragma unroll
            for (int n = 0; n < 4; ++n)
                acc[m][n] = __builtin_amdgcn_mfma_f32_16x16x32_bf16(af[m], bfv[n], acc[m][n], 0, 0, 0);
    }
    const float scale = 0.125f * 0.02209708691207961f;  // HD^-0.5 * S^-0.5
#pragma unroll
    for (int m = 0; m < 4; ++m)
#pragma unroll
        for (int n = 0; n < 4; ++n)
#pragma unroll
            for (int j = 0; j < 4; ++j) {
                int s = s0b + m * 16 + (lane >> 4) * 4 + j;
                int d = n * 16 + sl15;
                out[(size_t)(s * B + b) * H + h * 64 + d] = acc[m][n][j] * scale;
            }
}

// ---------------------------------------------------------------------------
extern "C" void kernel_launch(void* const* d_in, const int* in_sizes, int n_in,
                              void* d_out, int out_size, void* d_ws, size_t ws_size,
                              hipStream_t stream) {
    const float* hidden = (const float*)d_in[0];
    const float* W      = (const float*)d_in[1];
    const float* bias   = (const float*)d_in[2];
    float* out = (float*)d_out;

    ushort* Qb    = (ushort*)d_ws;                      //  8 MB  [bh][s][d]
    ushort* Ktd   = Qb + 4194304;                       //  8 MB  [bh][d][t]
    ushort* Vtd   = Ktd + 4194304;                      //  8 MB  [bh][d][t] (scan in place)
    float*  Mpart = (float*)(Vtd + 4194304);            //  2 MB  [4][bh][64][64]
    ushort* Abf   = (ushort*)(Mpart + 524288);          //  8 MB
    ushort* Wbf   = Abf + 4194304;                      //  6 MB
    // total ~40 MB of d_ws

    cast_both<<<(N8_A + N8_W + 255) / 256, 256, 0, stream>>>(hidden, W, Abf, Wbf);
    qkv_gemm_mfma<<<dim3(ROWS / 128, THREE_H / 128), 256, 0, stream>>>(Abf, Wbf, bias, Qb, Ktd, Vtd);
    vscan<<<512, 256, 0, stream>>>(Vtd);
    kvm_mfma<<<dim3(32, 4), 256, 0, stream>>>(Ktd, Vtd, Mpart);
    qm_mfma<<<dim3(32, 8), 256, 0, stream>>>(Qb, Mpart, out);
}